// Round 15
// baseline (2107.187 us; speedup 1.0000x reference)
//
#include <hip/hip_runtime.h>
#include <hip/hip_bf16.h>

// SetAbstraction: FPS -> kNN(32) -> gather -> 3x(conv1x1+BN+ReLU) -> maxpool(K)
// B=16 N=4096 S=1024 K=32 D_IN=64 MLP=[64,64,128]
// Mega-fused pipeline: fps publishes farr[s] -> knn waves consume, publish
// kdone[s] -> gemm1 blocks consume (z1 + stats1), all inside ONE kernel,
// hidden under the 550us serial FPS. Tail: stats1|gemm2|stats2|gemm3|stats3|final.

typedef __attribute__((ext_vector_type(8))) short bfrag;    // 8 bf16 (MFMA A/B)
typedef __attribute__((ext_vector_type(4))) float ffrag;    // 4 f32 (MFMA C/D)
typedef __attribute__((ext_vector_type(8))) unsigned short ushort8;

#define XS 104   // LDS row stride in bf16 elems: 16B-aligned, 2-way bank conflict (free)

__device__ inline unsigned short f2bf(float f){
  union { float f; unsigned u; } v; v.f = f;
  unsigned r = v.u + 0x7fffu + ((v.u >> 16) & 1u);   // RNE
  return (unsigned short)(r >> 16);
}
__device__ inline float bf2f(unsigned short h){
  union { unsigned u; float f; } v; v.u = ((unsigned)h) << 16; return v.f;
}

// ---- DPP cross-lane (VALU-rate; no LDS pipe)
template<int CTRL> __device__ __forceinline__ int dppi(int v){
  return __builtin_amdgcn_update_dpp(0, v, CTRL, 0xF, 0xF, true);
}
template<int CTRL> __device__ __forceinline__ float dppf(float v){
  return __int_as_float(dppi<CTRL>(__float_as_int(v)));
}
__device__ __forceinline__ float dppmax6(float v){   // lane63 = wave max
  v = fmaxf(v, dppf<0xB1>(v)); v = fmaxf(v, dppf<0x4E>(v));
  v = fmaxf(v, dppf<0x141>(v)); v = fmaxf(v, dppf<0x140>(v));
  v = fmaxf(v, dppf<0x142>(v)); v = fmaxf(v, dppf<0x143>(v));
  return v;
}
__device__ __forceinline__ float dppmin6(float v){   // lane63 = wave min
  v = fminf(v, dppf<0xB1>(v)); v = fminf(v, dppf<0x4E>(v));
  v = fminf(v, dppf<0x141>(v)); v = fminf(v, dppf<0x140>(v));
  v = fminf(v, dppf<0x142>(v)); v = fminf(v, dppf<0x143>(v));
  return v;
}
__device__ __forceinline__ unsigned dppminu6(unsigned v){
  unsigned o;
  o = (unsigned)dppi<0xB1>((int)v);  v = v < o ? v : o;
  o = (unsigned)dppi<0x4E>((int)v);  v = v < o ? v : o;
  o = (unsigned)dppi<0x141>((int)v); v = v < o ? v : o;
  o = (unsigned)dppi<0x140>((int)v); v = v < o ? v : o;
  o = (unsigned)dppi<0x142>((int)v); v = v < o ? v : o;
  o = (unsigned)dppi<0x143>((int)v); v = v < o ? v : o;
  return v;                                          // lane63 = wave min
}
__device__ __forceinline__ float dppadd4(float v){   // all lanes: 16-lane-row sum
  v += dppf<0xB1>(v); v += dppf<0x4E>(v); v += dppf<0x141>(v); v += dppf<0x140>(v);
  return v;
}
__device__ __forceinline__ float dppmax4(float v){
  v = fmaxf(v, dppf<0xB1>(v)); v = fmaxf(v, dppf<0x4E>(v));
  v = fmaxf(v, dppf<0x141>(v)); v = fmaxf(v, dppf<0x140>(v));
  return v;
}
__device__ __forceinline__ float dppmin4(float v){
  v = fminf(v, dppf<0xB1>(v)); v = fminf(v, dppf<0x4E>(v));
  v = fminf(v, dppf<0x141>(v)); v = fminf(v, dppf<0x140>(v));
  return v;
}

// ---------------- wconv: W -> bf16 + zero stats/flags
__global__ __launch_bounds__(256) void wconv_k(const float* __restrict__ W1,
    const float* __restrict__ W2, const float* __restrict__ W3,
    unsigned short* __restrict__ Wb1, unsigned short* __restrict__ Wb2,
    unsigned short* __restrict__ Wb3, float* __restrict__ stats,
    int* __restrict__ farr, int* __restrict__ kdone, int* __restrict__ tdone){
  const int t = threadIdx.x;
  for (int i = t; i < 64 * 96; i += 256){
    int r = i / 96, c = i % 96;
    Wb1[i] = (c < 67) ? f2bf(W1[r * 67 + c]) : (unsigned short)0;
  }
  for (int i = t; i < 64 * 64; i += 256) Wb2[i] = f2bf(W2[i]);
  for (int i = t; i < 128 * 64; i += 256) Wb3[i] = f2bf(W3[i]);
  for (int i = t; i < 32768; i += 256) stats[i] = 0.f;
  for (int i = t; i < 16384; i += 256){ farr[i] = 0; kdone[i] = 0; }
  if (t == 0) tdone[0] = 0;
}

// ---------------- mega-fused kernel, 3344 blocks x 512 thr, 1 block/CU (105KB LDS):
//  blocks    0..15   FPS (1/batch, serial 1024-step loop; publishes farr[s])
//  blocks   16..271  transpose pts -> pts_t bf16 (publishes tdone counter)
//  blocks  272..2319 kNN (8 waves, 1 centroid/wave, s-major; spins farr; publishes kdone)
//  blocks 2320..3343 gemm1 (512 cols, 16 s; spins kdone+tdone; writes z1 + stats1)
__global__ __launch_bounds__(512) void fused_k(const float* __restrict__ xyz,
    const float* __restrict__ pts, unsigned short* __restrict__ pts_t,
    float* __restrict__ out0,
    int* __restrict__ farr, int* __restrict__ kdone, int* __restrict__ tdone,
    int* __restrict__ knn,
    const unsigned short* __restrict__ Wb1, const float* __restrict__ b1,
    unsigned short* __restrict__ z1, float* __restrict__ stats1){
  __shared__ __align__(16) char smem[107520];   // >80KB: forces 1 block/CU
  const int t = threadIdx.x, bid = blockIdx.x;
  if (bid >= 2320){
    // ---------------- gemm1 path: 512 cols (16 s-values), s-major block order ----------------
    const int bid2 = bid - 2320;                 // 0..1023
    const int sg = bid2 >> 4, b = bid2 & 15;     // s = sg*16..+15
    const int col0 = sg * 512;
    unsigned short* Xl = (unsigned short*)smem;            // 512*XS*2 = 106496 B
    float* bsum = (float*)(smem + 106496);                 // 128 f32
    if (t < 128) bsum[t] = 0.f;
    if (t < 16){
      while (__hip_atomic_load(&kdone[b * 1024 + sg * 16 + t], __ATOMIC_ACQUIRE,
                               __HIP_MEMORY_SCOPE_AGENT) == 0)
        __builtin_amdgcn_s_sleep(16);
    }
    if (t == 16){
      while (__hip_atomic_load(tdone, __ATOMIC_ACQUIRE, __HIP_MEMORY_SCOPE_AGENT) < 256)
        __builtin_amdgcn_s_sleep(16);
    }
    __syncthreads();
    __threadfence();
    {
      const int col = col0 + t, s = col >> 5, k = col & 31;
      const int idx = __hip_atomic_load(&knn[((size_t)(b * 1024 + s)) * 32 + k],
                                        __ATOMIC_RELAXED, __HIP_MEMORY_SCOPE_AGENT);
      const int far = __hip_atomic_load(&farr[b * 1024 + s],
                                        __ATOMIC_RELAXED, __HIP_MEMORY_SCOPE_AGENT) - 1;
      const float* xb = xyz + (size_t)b * 3 * 4096;
      const unsigned short* src = pts_t + ((size_t)(b * 4096 + idx)) * 64;
      #pragma unroll
      for (int j = 0; j < 8; j++) *(ushort8*)&Xl[t * XS + j * 8] = *(const ushort8*)&src[j * 8];
      ushort8 tail = {0,0,0,0,0,0,0,0};
      tail[0] = f2bf(__fsub_rn(xb[idx],        xb[far]));
      tail[1] = f2bf(__fsub_rn(xb[4096 + idx], xb[4096 + far]));
      tail[2] = f2bf(__fsub_rn(xb[8192 + idx], xb[8192 + far]));
      *(ushort8*)&Xl[t * XS + 64] = tail;
      ushort8 zz8 = {0,0,0,0,0,0,0,0};
      *(ushort8*)&Xl[t * XS + 72] = zz8;
      *(ushort8*)&Xl[t * XS + 80] = zz8;
      *(ushort8*)&Xl[t * XS + 88] = zz8;
    }
    const int lane = t & 63, lr = lane & 15, lg = lane >> 4;
    const int colw = (t >> 6) * 64;              // 8 waves x 64 cols
    bfrag a[4][3];
    #pragma unroll
    for (int r = 0; r < 4; r++)
      #pragma unroll
      for (int kk = 0; kk < 3; kk++)
        a[r][kk] = *(const bfrag*)&Wb1[(16 * r + lr) * 96 + kk * 32 + lg * 8];
    __syncthreads();
    ffrag acc[4][4] = {};
    #pragma unroll
    for (int kk = 0; kk < 3; kk++){
      bfrag bb[4];
      #pragma unroll
      for (int cf = 0; cf < 4; cf++)
        bb[cf] = *(const bfrag*)&Xl[(colw + cf * 16 + lr) * XS + kk * 32 + lg * 8];
      #pragma unroll
      for (int r = 0; r < 4; r++)
        #pragma unroll
        for (int cf = 0; cf < 4; cf++)
          acc[r][cf] = __builtin_amdgcn_mfma_f32_16x16x32_bf16(a[r][kk], bb[cf], acc[r][cf], 0, 0, 0);
    }
    #pragma unroll
    for (int r = 0; r < 4; r++){
      const int o0 = 16 * r + 4 * lg;
      const ffrag bv = *(const ffrag*)&b1[o0];
      float sm[4] = {0,0,0,0}, sq[4] = {0,0,0,0};
      #pragma unroll
      for (int cf = 0; cf < 4; cf++){
        const int col = col0 + colw + cf * 16 + lr;
        unsigned pk[2];
        #pragma unroll
        for (int e = 0; e < 4; e++){
          float v = acc[r][cf][e] + bv[e];
          sm[e] += v; sq[e] += v * v;
          ((unsigned short*)pk)[e] = f2bf(v);
        }
        *(unsigned long long*)&z1[((size_t)(b * 32768) + col) * 64 + o0] = *(unsigned long long*)pk;
      }
      #pragma unroll
      for (int e = 0; e < 4; e++){
        float s1 = dppadd4(sm[e]);
        float q1 = dppadd4(sq[e]);
        if (lr == 0){ atomicAdd(&bsum[(o0 + e) * 2], s1); atomicAdd(&bsum[(o0 + e) * 2 + 1], q1); }
      }
    }
    __syncthreads();
    if (t < 128) atomicAdd(&stats1[sg * 128 + t], bsum[t]);
    return;
  }
  if (bid >= 272){
    // ---------------- kNN path (8 waves/block, 1 centroid/wave, s-major) ----------------
    const int bid2 = bid - 272;
    const int w = t >> 6, lane = t & 63;
    const int b = bid2 & 15;
    const int s = (bid2 >> 4) * 8 + w;
    const float* xb = xyz + (size_t)b * 3 * 4096;
    int fidx;
    while ((fidx = __hip_atomic_load(&farr[b * 1024 + s], __ATOMIC_ACQUIRE,
                                     __HIP_MEMORY_SCOPE_AGENT)) == 0)
      __builtin_amdgcn_s_sleep(16);
    const int far = fidx - 1;
    const float cx = xb[far], cy = xb[4096 + far], cz = xb[8192 + far];
    const float sqc = __fadd_rn(__fadd_rn(__fmul_rn(cx, cx), __fmul_rn(cy, cy)), __fmul_rn(cz, cz));
    float d[64];
    float m1 = 3e38f, m2 = 3e38f, m3 = 3e38f, m4 = 3e38f;
    int i1 = 0x7fffffff, i2 = 0x7fffffff, i3 = 0x7fffffff, i4 = 0x7fffffff;
    #pragma unroll
    for (int j = 0; j < 64; j++){
      int i = j * 64 + lane;
      float x = xb[i], y = xb[4096 + i], z = xb[8192 + i];
      float sqn = __fadd_rn(__fadd_rn(__fmul_rn(x, x), __fmul_rn(y, y)), __fmul_rn(z, z));
      float dot = __fadd_rn(__fadd_rn(__fmul_rn(cx, x), __fmul_rn(cy, y)), __fmul_rn(cz, z));
      float dd = __fsub_rn(__fadd_rn(sqc, sqn), __fmul_rn(2.0f, dot));
      d[j] = dd;
      bool c1 = dd < m1, c2 = dd < m2, c3 = dd < m3, c4 = dd < m4;
      m4 = c4 ? (c3 ? m3 : dd) : m4;  i4 = c4 ? (c3 ? i3 : i) : i4;
      m3 = c3 ? (c2 ? m2 : dd) : m3;  i3 = c3 ? (c2 ? i2 : i) : i3;
      m2 = c2 ? (c1 ? m1 : dd) : m2;  i2 = c2 ? (c1 ? i1 : i) : i2;
      m1 = c1 ? dd : m1;              i1 = c1 ? i : i1;
    }
    unsigned long long taken = 0ull;
    int out_idx = 0;
    #pragma unroll 1
    for (int r = 0; r < 32; r++){
      const float gred = dppmin6(m1);
      const float gmin = __int_as_float(__builtin_amdgcn_readlane(__float_as_int(gred), 63));
      const bool cand = (m1 == gmin);
      const unsigned long long cm = __ballot(cand);
      int widx;
      if (__popcll(cm) == 1){
        widx = __builtin_amdgcn_readlane(i1, (int)(__ffsll(cm) - 1));
      } else {                            // exact-tie rare path: min index among candidates
        unsigned ci = cand ? (unsigned)i1 : 0xFFFFFFFFu;
        widx = (int)__builtin_amdgcn_readlane((int)dppminu6(ci), 63);
      }
      if (lane == r) out_idx = widx;
      if (i1 == widx){                    // unique owner pops
        taken |= 1ull << (widx >> 6);
        m1 = m2; i1 = i2; m2 = m3; i2 = i3; m3 = m4; i3 = i4;
        m4 = 3e38f; i4 = 0x7fffffff;
        if (i1 == 0x7fffffff){            // spares exhausted (rare): refill top-4
          m1 = 3e38f; m2 = 3e38f; m3 = 3e38f; m4 = 3e38f;
          i1 = 0x7fffffff; i2 = 0x7fffffff; i3 = 0x7fffffff; i4 = 0x7fffffff;
          #pragma unroll
          for (int j = 0; j < 64; j++){
            if (!((taken >> j) & 1ull)){
              float dd = d[j]; int i = j * 64 + lane;
              bool c1 = dd < m1, c2 = dd < m2, c3 = dd < m3, c4 = dd < m4;
              m4 = c4 ? (c3 ? m3 : dd) : m4;  i4 = c4 ? (c3 ? i3 : i) : i4;
              m3 = c3 ? (c2 ? m2 : dd) : m3;  i3 = c3 ? (c2 ? i2 : i) : i3;
              m2 = c2 ? (c1 ? m1 : dd) : m2;  i2 = c2 ? (c1 ? i1 : i) : i2;
              m1 = c1 ? dd : m1;              i1 = c1 ? i : i1;
            }
          }
        }
      }
    }
    if (lane < 32)
      __hip_atomic_store(&knn[((size_t)(b * 1024 + s)) * 32 + lane], out_idx,
                         __ATOMIC_RELAXED, __HIP_MEMORY_SCOPE_AGENT);
    __threadfence();
    if (lane == 0)
      __hip_atomic_store(&kdone[b * 1024 + s], 1, __ATOMIC_RELEASE, __HIP_MEMORY_SCOPE_AGENT);
    return;
  }
  if (bid >= 16){
    // ---------------- transpose path (512 thr) ----------------
    unsigned short* tile = (unsigned short*)smem;       // 64*258*2 = 33024 B
    const int bid2 = bid - 16;
    const int b = bid2 >> 4, n0 = (bid2 & 15) * 256;
    {
      const int n = t & 255, ch = t >> 8;               // ch in {0,1}
      for (int it = 0; it < 32; it++){
        int c = it * 2 + ch;
        tile[c * 258 + n] = f2bf(pts[((size_t)(b * 64 + c)) * 4096 + n0 + n]);
      }
    }
    __syncthreads();
    const int nn = t >> 5, c2 = (t & 31) * 2;           // nn 0..15
    for (int rep = 0; rep < 16; rep++){
      int n = rep * 16 + nn;
      unsigned lo = tile[c2 * 258 + n], hi = tile[(c2 + 1) * 258 + n];
      ((unsigned*)pts_t)[(((size_t)(b * 4096 + n0 + n)) * 64 + c2) >> 1] = lo | (hi << 16);
    }
    __syncthreads();                                    // all stores drained
    if (t == 0){
      __threadfence();
      atomicAdd(tdone, 1);
    }
    return;
  }
  // ---------------- FPS path (512 thr, 8 pts/thr; R8-proven) ----------------
  float4* xl4 = (float4*)smem;                               // 65536 B
  unsigned long long* skey = (unsigned long long*)(smem + 65536);   // 32 B
  unsigned short* farhist = (unsigned short*)(smem + 65568);        // 2048 B
  const int b = bid;
  {
    const float* xb = xyz + (size_t)b * 3 * 4096;
    for (int j = 0; j < 8; j++){
      int i = j * 512 + t;
      float4 v; v.x = xb[i]; v.y = xb[4096 + i]; v.z = xb[8192 + i]; v.w = 0.f;
      xl4[i] = v;
    }
  }
  if (t == 0){
    skey[0] = 0xFFFFFFFF00000FFFull;   // lo=4095 -> far=0
    skey[1] = 0ull; skey[2] = 0ull; skey[3] = 0ull;
  }
  __syncthreads();
  float px[8], py[8], pz[8], dist[8];
  #pragma unroll
  for (int j = 0; j < 8; j++){
    int i = j * 512 + t;
    float4 v = xl4[i];
    px[j] = v.x; py[j] = v.y; pz[j] = v.z; dist[j] = 1e10f;
  }
  const unsigned a0 = 4095u - t;     // inv_j = a0 - j*512
  for (int s = 0; s < 1024; s++){
    const unsigned long long kg = skey[s & 3];
    const int far = 4095 - (int)(unsigned)(kg & 0xFFFFFFFFull);
    const float4 c4 = xl4[far];
    const float cx = c4.x, cy = c4.y, cz = c4.z;
    if (t == 0){
      farhist[s] = (unsigned short)far;
      skey[(s + 2) & 3] = 0ull;        // reset ring slot for step s+1's writers
      __hip_atomic_store(&farr[b * 1024 + s], far + 1,
                         __ATOMIC_RELEASE, __HIP_MEMORY_SCOPE_AGENT);   // publish
    }
    float vm = -1.f;
    #pragma unroll
    for (int j = 0; j < 8; j++){
      float dx = __fsub_rn(px[j], cx), dy = __fsub_rn(py[j], cy), dz = __fsub_rn(pz[j], cz);
      float d = __fadd_rn(__fadd_rn(__fmul_rn(dx, dx), __fmul_rn(dy, dy)), __fmul_rn(dz, dz));
      float dm = fminf(dist[j], d); dist[j] = dm;
      vm = fmaxf(vm, dm);
    }
    const float wred = dppmax6(vm);
    const float wvm = __int_as_float(__builtin_amdgcn_readlane(__float_as_int(wred), 63));
    if (vm == wvm){                     // usually 1 lane/wave
      unsigned inv = 0u;
      #pragma unroll
      for (int j = 7; j >= 0; j--)
        if (dist[j] == wvm) inv = a0 - (unsigned)(j * 512);  // smallest j -> largest inv -> smallest idx
      atomicMax(&skey[(s + 1) & 3],
                (((unsigned long long)__float_as_uint(wvm)) << 32) | inv);
    }
    __syncthreads();
  }
  for (int s2 = t; s2 < 1024; s2 += 512){
    const int f = farhist[s2];
    const float4 c4 = xl4[f];
    out0[(b * 3 + 0) * 1024 + s2] = c4.x;
    out0[(b * 3 + 1) * 1024 + s2] = c4.y;
    out0[(b * 3 + 2) * 1024 + s2] = c4.z;
  }
}

// GEMM2: x = relu(a1*z1+c1), 64->64
__global__ __launch_bounds__(256) void gemm2_k(const unsigned short* __restrict__ z1,
    const unsigned short* __restrict__ Wb2, const float* __restrict__ b2, const float* __restrict__ p1,
    unsigned short* __restrict__ z2, float* __restrict__ stats){
  __shared__ unsigned short Xl[256 * XS];
  __shared__ float bsum[128];
  __shared__ float pa[64], pc[64];
  const int t = threadIdx.x, bid = blockIdx.x;
  const int b = bid >> 7, col0 = (bid & 127) * 256;
  if (t < 128) bsum[t] = 0.f;
  if (t < 64){ pa[t] = p1[t * 2]; pc[t] = p1[t * 2 + 1]; }
  const int lane = t & 63, lr = lane & 15, lg = lane >> 4;
  const int colw = (t >> 6) * 64;
  bfrag a[4][2];
  #pragma unroll
  for (int r = 0; r < 4; r++)
    #pragma unroll
    for (int kk = 0; kk < 2; kk++)
      a[r][kk] = *(const bfrag*)&Wb2[(16 * r + lr) * 64 + kk * 32 + lg * 8];
  __syncthreads();   // pa/pc ready
  {
    const size_t gcol = (size_t)b * 32768 + col0 + t;
    const unsigned short* src = z1 + gcol * 64;
    #pragma unroll
    for (int j = 0; j < 8; j++){
      ushort8 zv = *(const ushort8*)&src[j * 8];
      unsigned short ov[8];
      #pragma unroll
      for (int e = 0; e < 8; e++){
        int ch = j * 8 + e;
        float v = fmaxf(fmaf(pa[ch], bf2f(zv[e]), pc[ch]), 0.f);
        ov[e] = f2bf(v);
      }
      *(ushort8*)&Xl[t * XS + j * 8] = *(ushort8*)ov;
    }
  }
  __syncthreads();
  ffrag acc[4][4] = {};
  #pragma unroll
  for (int kk = 0; kk < 2; kk++){
    bfrag bb[4];
    #pragma unroll
    for (int cf = 0; cf < 4; cf++)
      bb[cf] = *(const bfrag*)&Xl[(colw + cf * 16 + lr) * XS + kk * 32 + lg * 8];
    #pragma unroll
    for (int r = 0; r < 4; r++)
      #pragma unroll
      for (int cf = 0; cf < 4; cf++)
        acc[r][cf] = __builtin_amdgcn_mfma_f32_16x16x32_bf16(a[r][kk], bb[cf], acc[r][cf], 0, 0, 0);
  }
  #pragma unroll
  for (int r = 0; r < 4; r++){
    const int o0 = 16 * r + 4 * lg;
    const ffrag bv = *(const ffrag*)&b2[o0];
    float sm[4] = {0,0,0,0}, sq[4] = {0,0,0,0};
    #pragma unroll
    for (int cf = 0; cf < 4; cf++){
      const int col = col0 + colw + cf * 16 + lr;
      unsigned pk[2];
      #pragma unroll
      for (int e = 0; e < 4; e++){
        float v = acc[r][cf][e] + bv[e];
        sm[e] += v; sq[e] += v * v;
        ((unsigned short*)pk)[e] = f2bf(v);
      }
      *(unsigned long long*)&z2[((size_t)(b * 32768) + col) * 64 + o0] = *(unsigned long long*)pk;
    }
    #pragma unroll
    for (int e = 0; e < 4; e++){
      float s1 = dppadd4(sm[e]);
      float q1 = dppadd4(sq[e]);
      if (lr == 0){ atomicAdd(&bsum[(o0 + e) * 2], s1); atomicAdd(&bsum[(o0 + e) * 2 + 1], q1); }
    }
  }
  __syncthreads();
  if (t < 128) atomicAdd(&stats[(bid & 63) * 128 + t], bsum[t]);
}

// GEMM3: 64->128, fused max/min over K (z3 never materialized)
__global__ __launch_bounds__(256) void gemm3_k(const unsigned short* __restrict__ z2,
    const unsigned short* __restrict__ Wb3, const float* __restrict__ b3, const float* __restrict__ p2,
    float* __restrict__ maxz, float* __restrict__ minz, float* __restrict__ stats){
  __shared__ unsigned short Xl[128 * XS];
  __shared__ float bsum[256];
  __shared__ float pa[64], pc[64];
  const int t = threadIdx.x, bid = blockIdx.x;
  const int b = bid >> 8, col0 = (bid & 255) * 128;
  bsum[t] = 0.f;
  if (t < 64){ pa[t] = p2[t * 2]; pc[t] = p2[t * 2 + 1]; }
  const int lane = t & 63, lr = lane & 15, lg = lane >> 4;
  const int w = t >> 6, wr = w >> 1, wc = w & 1;
  bfrag a[4][2];
  #pragma unroll
  for (int r = 0; r < 4; r++)
    #pragma unroll
    for (int kk = 0; kk < 2; kk++)
      a[r][kk] = *(const bfrag*)&Wb3[(wr * 64 + 16 * r + lr) * 64 + kk * 32 + lg * 8];
  __syncthreads();
  {
    const int colL = t & 127, half = t >> 7;
    const size_t gcol = (size_t)b * 32768 + col0 + colL;
    const unsigned short* src = z2 + gcol * 64 + half * 32;
    #pragma unroll
    for (int j = 0; j < 4; j++){
      ushort8 zv = *(const ushort8*)&src[j * 8];
      unsigned short ov[8];
      #pragma unroll
      for (int e = 0; e < 8; e++){
        int ch = half * 32 + j * 8 + e;
        float v = fmaxf(fmaf(pa[ch], bf2f(zv[e]), pc[ch]), 0.f);
        ov[e] = f2bf(v);
      }
      *(ushort8*)&Xl[colL * XS + half * 32 + j * 8] = *(ushort8*)ov;
    }
  }
  __syncthreads();
  ffrag acc[4][4] = {};
  #pragma unroll
  for (int kk = 0; kk < 2; kk++){
    bfrag bb[4];
    #pragma unroll
    for (int cf = 0; cf < 4; cf++)
      bb[cf] = *(const bfrag*)&Xl[(wc * 64 + cf * 16 + lr) * XS + kk * 32 + lg * 8];
    #pragma unroll
    for (int r = 0; r < 4; r++)
      #pragma unroll
      for (int cf = 0; cf < 4; cf++)
        acc[r][cf] = __builtin_amdgcn_mfma_f32_16x16x32_bf16(a[r][kk], bb[cf], acc[r][cf], 0, 0, 0);
  }
  const int s0 = (col0 + wc * 64) >> 5;    // 64 cols = 2 s values (K=32)
  #pragma unroll
  for (int r = 0; r < 4; r++){
    const int o0 = wr * 64 + 16 * r + 4 * lg;
    const ffrag bv = *(const ffrag*)&b3[(o0 & 127)];
    float vv[4][4];
    float sm[4] = {0,0,0,0}, sq[4] = {0,0,0,0};
    #pragma unroll
    for (int cf = 0; cf < 4; cf++)
      #pragma unroll
      for (int e = 0; e < 4; e++){
        float v = acc[r][cf][e] + bv[e];
        vv[cf][e] = v; sm[e] += v; sq[e] += v * v;
      }
    #pragma unroll
    for (int e = 0; e < 4; e++){
      float s1 = dppadd4(sm[e]);
      float q1 = dppadd4(sq[e]);
      if (lr == 0){ atomicAdd(&bsum[((o0 + e) & 127) * 2], s1); atomicAdd(&bsum[((o0 + e) & 127) * 2 + 1], q1); }
    }
    #pragma unroll
    for (int si = 0; si < 2; si++){
      ffrag mx, mn;
      #pragma unroll
      for (int e = 0; e < 4; e++){
        mx[e] = dppmax4(fmaxf(vv[si * 2][e], vv[si * 2 + 1][e]));
        mn[e] = dppmin4(fminf(vv[si * 2][e], vv[si * 2 + 1][e]));
      }
      if (lr == 0){
        *(ffrag*)&maxz[((size_t)(b * 1024) + s0 + si) * 128 + o0] = mx;
        *(ffrag*)&minz[((size_t)(b * 1024) + s0 + si) * 128 + o0] = mn;
      }
    }
  }
  __syncthreads();
  atomicAdd(&stats[(bid & 63) * 256 + t], bsum[t]);
}

// stats -> (a, c) affine params
template<int CH>
__global__ void stats_k(const float* __restrict__ stats, const float* __restrict__ gamma,
                        const float* __restrict__ beta, float* __restrict__ params){
  const int t = threadIdx.x;
  float sm = 0.f, sq = 0.f;
  for (int sl = 0; sl < 64; sl++){
    sm += stats[sl * (CH * 2) + t * 2];
    sq += stats[sl * (CH * 2) + t * 2 + 1];
  }
  const float cnt = 524288.f;
  float mean = sm / cnt;
  float var = sq / cnt - mean * mean;
  if (var < 0.f) var = 0.f;
  float inv = gamma[t] / sqrtf(var + 1e-5f);
  params[t * 2] = inv;
  params[t * 2 + 1] = beta[t] - mean * inv;
}

// final: out1[b][o][s] = relu(a3*sel+c3), LDS transpose for coalesced writes
__global__ __launch_bounds__(256) void final_k(const float* __restrict__ maxz,
    const float* __restrict__ minz, const float* __restrict__ p3, float* __restrict__ out1){
  __shared__ float tile[64][129];
  __shared__ float pa[128], pc[128];
  const int t = threadIdx.x, bid = blockIdx.x;
  const int b = bid >> 4, s0 = (bid & 15) * 64;
  if (t < 128){ pa[t] = p3[t * 2]; pc[t] = p3[t * 2 + 1]; }
  __syncthreads();
  const int o = t & 127, rr = t >> 7;
  for (int it = 0; it < 32; it++){
    int srow = it * 2 + rr;
    size_t base = ((size_t)(b * 1024) + s0 + srow) * 128 + o;
    float aa = pa[o], cc = pc[o];
    float m = (aa >= 0.f) ? maxz[base] : minz[base];
    tile[srow][o] = fmaxf(fmaf(aa, m, cc), 0.f);
  }
  __syncthreads();
  const int sc = t & 63, og = t >> 6;
  for (int it = 0; it < 32; it++){
    int o2 = it * 4 + og;
    out1[((size_t)(b * 128 + o2)) * 1024 + s0 + sc] = tile[sc][o2];
  }
}

extern "C" void kernel_launch(void* const* d_in, const int* in_sizes, int n_in,
                              void* d_out, int out_size, void* d_ws, size_t ws_size,
                              hipStream_t stream){
  const float* xyz = (const float*)d_in[0];
  const float* pts = (const float*)d_in[1];
  const float* W1 = (const float*)d_in[2];  const float* b1 = (const float*)d_in[3];
  const float* g1 = (const float*)d_in[4];  const float* be1 = (const float*)d_in[5];
  const float* W2 = (const float*)d_in[6];  const float* b2 = (const float*)d_in[7];
  const float* g2 = (const float*)d_in[8];  const float* be2 = (const float*)d_in[9];
  const float* W3 = (const float*)d_in[10]; const float* b3 = (const float*)d_in[11];
  const float* g3 = (const float*)d_in[12]; const float* be3 = (const float*)d_in[13];
  float* out0 = (float*)d_out;
  float* out1 = out0 + 16 * 3 * 1024;

  char* w = (char*)d_ws;
  size_t off = 0;
  auto alloc = [&](size_t bytes){ void* p = w + off; off = (off + bytes + 255) & ~(size_t)255; return p; };
  unsigned short* pts_t = (unsigned short*)alloc(8388608);      // [B][N][64] bf16
  int*   knn            = (int*)alloc(2097152);                  // [B][S][32]
  unsigned short* z1    = (unsigned short*)alloc(67108864);      // [B*S*K][64] bf16
  unsigned short* z2    = (unsigned short*)alloc(67108864);
  float* maxz           = (float*)alloc(8388608);                // [B][S][128]
  float* minz           = (float*)alloc(8388608);
  unsigned short* Wb1   = (unsigned short*)alloc(12288);         // [64][96] bf16
  unsigned short* Wb2   = (unsigned short*)alloc(8192);          // [64][64]
  unsigned short* Wb3   = (unsigned short*)alloc(16384);         // [128][64]
  float* stats          = (float*)alloc(131072);                 // s1[64][128], s2 same, s3[64][256]
  float* params         = (float*)alloc(2048);
  int*   farr           = (int*)alloc(65536);                    // [B][S] fps progress (far+1)
  int*   kdone          = (int*)alloc(65536);                    // [B][S] knn done flag
  int*   tdone          = (int*)alloc(256);                      // transpose done counter
  if (ws_size < off) return;

  float* stats1 = stats;            // 8192 floats
  float* stats2 = stats + 8192;     // 8192 floats
  float* stats3 = stats + 16384;    // 16384 floats
  float* p1 = params, *p2 = params + 128, *p3 = params + 256;

  wconv_k<<<1, 256, 0, stream>>>(W1, W2, W3, Wb1, Wb2, Wb3, stats, farr, kdone, tdone);
  fused_k<<<3344, 512, 0, stream>>>(xyz, pts, pts_t, out0, farr, kdone, tdone, knn,
                                    Wb1, b1, z1, stats1);
  stats_k<64><<<1, 64, 0, stream>>>(stats1, g1, be1, p1);
  gemm2_k<<<2048, 256, 0, stream>>>(z1, Wb2, b2, p1, z2, stats2);
  stats_k<64><<<1, 64, 0, stream>>>(stats2, g2, be2, p2);
  gemm3_k<<<4096, 256, 0, stream>>>(z2, Wb3, b3, p2, maxz, minz, stats3);
  stats_k<128><<<1, 128, 0, stream>>>(stats3, g3, be3, p3);
  final_k<<<256, 256, 0, stream>>>(maxz, minz, p3, out1);
}

// Round 16
// 1571.570 us; speedup vs baseline: 1.3408x; 1.3408x over previous
//
#include <hip/hip_runtime.h>
#include <hip/hip_bf16.h>

// SetAbstraction: FPS -> kNN(32) -> gather -> 3x(conv1x1+BN+ReLU) -> maxpool(K)
// B=16 N=4096 S=1024 K=32 D_IN=64 MLP=[64,64,128]
// Mega-fused pipeline: fps publishes farr[s]; COMBINED blocks (one per 16 s)
// run kNN (results in LDS) then gemm1 for those s — consumers only wait on
// the always-resident fps + front-dispatched transpose (no slot starvation).
// Tail: stats1 | gemm2 | stats2 | gemm3 | stats3 | final.

typedef __attribute__((ext_vector_type(8))) short bfrag;    // 8 bf16 (MFMA A/B)
typedef __attribute__((ext_vector_type(4))) float ffrag;    // 4 f32 (MFMA C/D)
typedef __attribute__((ext_vector_type(8))) unsigned short ushort8;

#define XS 104   // LDS row stride in bf16 elems: 16B-aligned, 2-way bank conflict (free)

__device__ inline unsigned short f2bf(float f){
  union { float f; unsigned u; } v; v.f = f;
  unsigned r = v.u + 0x7fffu + ((v.u >> 16) & 1u);   // RNE
  return (unsigned short)(r >> 16);
}
__device__ inline float bf2f(unsigned short h){
  union { unsigned u; float f; } v; v.u = ((unsigned)h) << 16; return v.f;
}

// ---- DPP cross-lane (VALU-rate; no LDS pipe)
template<int CTRL> __device__ __forceinline__ int dppi(int v){
  return __builtin_amdgcn_update_dpp(0, v, CTRL, 0xF, 0xF, true);
}
template<int CTRL> __device__ __forceinline__ float dppf(float v){
  return __int_as_float(dppi<CTRL>(__float_as_int(v)));
}
__device__ __forceinline__ float dppmax6(float v){   // lane63 = wave max
  v = fmaxf(v, dppf<0xB1>(v)); v = fmaxf(v, dppf<0x4E>(v));
  v = fmaxf(v, dppf<0x141>(v)); v = fmaxf(v, dppf<0x140>(v));
  v = fmaxf(v, dppf<0x142>(v)); v = fmaxf(v, dppf<0x143>(v));
  return v;
}
__device__ __forceinline__ float dppmin6(float v){   // lane63 = wave min
  v = fminf(v, dppf<0xB1>(v)); v = fminf(v, dppf<0x4E>(v));
  v = fminf(v, dppf<0x141>(v)); v = fminf(v, dppf<0x140>(v));
  v = fminf(v, dppf<0x142>(v)); v = fminf(v, dppf<0x143>(v));
  return v;
}
__device__ __forceinline__ unsigned dppminu6(unsigned v){
  unsigned o;
  o = (unsigned)dppi<0xB1>((int)v);  v = v < o ? v : o;
  o = (unsigned)dppi<0x4E>((int)v);  v = v < o ? v : o;
  o = (unsigned)dppi<0x141>((int)v); v = v < o ? v : o;
  o = (unsigned)dppi<0x140>((int)v); v = v < o ? v : o;
  o = (unsigned)dppi<0x142>((int)v); v = v < o ? v : o;
  o = (unsigned)dppi<0x143>((int)v); v = v < o ? v : o;
  return v;                                          // lane63 = wave min
}
__device__ __forceinline__ float dppadd4(float v){   // all lanes: 16-lane-row sum
  v += dppf<0xB1>(v); v += dppf<0x4E>(v); v += dppf<0x141>(v); v += dppf<0x140>(v);
  return v;
}
__device__ __forceinline__ float dppmax4(float v){
  v = fmaxf(v, dppf<0xB1>(v)); v = fmaxf(v, dppf<0x4E>(v));
  v = fmaxf(v, dppf<0x141>(v)); v = fmaxf(v, dppf<0x140>(v));
  return v;
}
__device__ __forceinline__ float dppmin4(float v){
  v = fminf(v, dppf<0xB1>(v)); v = fminf(v, dppf<0x4E>(v));
  v = fminf(v, dppf<0x141>(v)); v = fminf(v, dppf<0x140>(v));
  return v;
}

// ---------------- wconv: W -> bf16 + zero stats/flags
__global__ __launch_bounds__(256) void wconv_k(const float* __restrict__ W1,
    const float* __restrict__ W2, const float* __restrict__ W3,
    unsigned short* __restrict__ Wb1, unsigned short* __restrict__ Wb2,
    unsigned short* __restrict__ Wb3, float* __restrict__ stats,
    int* __restrict__ farr, int* __restrict__ tdone){
  const int t = threadIdx.x;
  for (int i = t; i < 64 * 96; i += 256){
    int r = i / 96, c = i % 96;
    Wb1[i] = (c < 67) ? f2bf(W1[r * 67 + c]) : (unsigned short)0;
  }
  for (int i = t; i < 64 * 64; i += 256) Wb2[i] = f2bf(W2[i]);
  for (int i = t; i < 128 * 64; i += 256) Wb3[i] = f2bf(W3[i]);
  for (int i = t; i < 32768; i += 256) stats[i] = 0.f;
  for (int i = t; i < 16384; i += 256) farr[i] = 0;
  if (t == 0) tdone[0] = 0;
}

// ---------------- mega-fused kernel, 1296 blocks x 512 thr, 1 block/CU (~107KB LDS):
//  blocks   0..15   FPS (1/batch, serial 1024-step loop; publishes farr[s])
//  blocks  16..271  transpose pts -> pts_t bf16 (publishes tdone counter)
//  blocks 272..1295 COMBINED: kNN for 16 s (2/wave, results in LDS) then gemm1
//                   for those 512 cols (z1 + stats1). s-major block order.
__global__ __launch_bounds__(512, 2) void fused_k(const float* __restrict__ xyz,
    const float* __restrict__ pts, unsigned short* __restrict__ pts_t,
    float* __restrict__ out0,
    int* __restrict__ farr, int* __restrict__ tdone,
    const unsigned short* __restrict__ Wb1, const float* __restrict__ b1,
    unsigned short* __restrict__ z1, float* __restrict__ stats1){
  __shared__ __align__(16) char smem[109184];   // >80KB: forces 1 block/CU
  const int t = threadIdx.x, bid = blockIdx.x;
  if (bid >= 272){
    // ---------------- COMBINED kNN + gemm1 path ----------------
    const int bid2 = bid - 272;                 // 0..1023
    const int sg = bid2 >> 4, b = bid2 & 15;    // s = sg*16 .. sg*16+15
    unsigned short* Xl = (unsigned short*)smem;            // 512*XS*2 = 106496 B
    float* bsum = (float*)(smem + 106496);                 // 128 f32 (512 B)
    int* knnls  = (int*)(smem + 107008);                   // 16*32 ints (2048 B)
    int* farls  = (int*)(smem + 109056);                   // 16 ints (64 B)
    const int w = t >> 6, lane = t & 63;
    const float* xb = xyz + (size_t)b * 3 * 4096;
    if (t < 128) bsum[t] = 0.f;
    // ---- kNN phase: each wave handles 2 s-values sequentially
    for (int rep = 0; rep < 2; rep++){
      const int s_local = w + rep * 8;
      const int s = sg * 16 + s_local;
      int fidx;
      while ((fidx = atomicAdd(&farr[b * 1024 + s], 0)) == 0)
        __builtin_amdgcn_s_sleep(16);
      const int far = fidx - 1;
      if (lane == 0) farls[s_local] = far;
      const float cx = xb[far], cy = xb[4096 + far], cz = xb[8192 + far];
      const float sqc = __fadd_rn(__fadd_rn(__fmul_rn(cx, cx), __fmul_rn(cy, cy)), __fmul_rn(cz, cz));
      float d[64];
      float m1 = 3e38f, m2 = 3e38f, m3 = 3e38f, m4 = 3e38f;
      int i1 = 0x7fffffff, i2 = 0x7fffffff, i3 = 0x7fffffff, i4 = 0x7fffffff;
      #pragma unroll
      for (int j = 0; j < 64; j++){
        int i = j * 64 + lane;
        float x = xb[i], y = xb[4096 + i], z = xb[8192 + i];
        float sqn = __fadd_rn(__fadd_rn(__fmul_rn(x, x), __fmul_rn(y, y)), __fmul_rn(z, z));
        float dot = __fadd_rn(__fadd_rn(__fmul_rn(cx, x), __fmul_rn(cy, y)), __fmul_rn(cz, z));
        float dd = __fsub_rn(__fadd_rn(sqc, sqn), __fmul_rn(2.0f, dot));
        d[j] = dd;
        bool c1 = dd < m1, c2 = dd < m2, c3 = dd < m3, c4 = dd < m4;
        m4 = c4 ? (c3 ? m3 : dd) : m4;  i4 = c4 ? (c3 ? i3 : i) : i4;
        m3 = c3 ? (c2 ? m2 : dd) : m3;  i3 = c3 ? (c2 ? i2 : i) : i3;
        m2 = c2 ? (c1 ? m1 : dd) : m2;  i2 = c2 ? (c1 ? i1 : i) : i2;
        m1 = c1 ? dd : m1;              i1 = c1 ? i : i1;
      }
      unsigned long long taken = 0ull;
      int out_idx = 0;
      #pragma unroll 1
      for (int r = 0; r < 32; r++){
        const float gred = dppmin6(m1);
        const float gmin = __int_as_float(__builtin_amdgcn_readlane(__float_as_int(gred), 63));
        const bool cand = (m1 == gmin);
        const unsigned long long cm = __ballot(cand);
        int widx;
        if (__popcll(cm) == 1){
          widx = __builtin_amdgcn_readlane(i1, (int)(__ffsll(cm) - 1));
        } else {                            // exact-tie rare path: min index among candidates
          unsigned ci = cand ? (unsigned)i1 : 0xFFFFFFFFu;
          widx = (int)__builtin_amdgcn_readlane((int)dppminu6(ci), 63);
        }
        if (lane == r) out_idx = widx;
        if (i1 == widx){                    // unique owner pops
          taken |= 1ull << (widx >> 6);
          m1 = m2; i1 = i2; m2 = m3; i2 = i3; m3 = m4; i3 = i4;
          m4 = 3e38f; i4 = 0x7fffffff;
          if (i1 == 0x7fffffff){            // spares exhausted (rare): refill top-4
            m1 = 3e38f; m2 = 3e38f; m3 = 3e38f; m4 = 3e38f;
            i1 = 0x7fffffff; i2 = 0x7fffffff; i3 = 0x7fffffff; i4 = 0x7fffffff;
            #pragma unroll
            for (int j = 0; j < 64; j++){
              if (!((taken >> j) & 1ull)){
                float dd = d[j]; int i = j * 64 + lane;
                bool c1 = dd < m1, c2 = dd < m2, c3 = dd < m3, c4 = dd < m4;
                m4 = c4 ? (c3 ? m3 : dd) : m4;  i4 = c4 ? (c3 ? i3 : i) : i4;
                m3 = c3 ? (c2 ? m2 : dd) : m3;  i3 = c3 ? (c2 ? i2 : i) : i3;
                m2 = c2 ? (c1 ? m1 : dd) : m2;  i2 = c2 ? (c1 ? i1 : i) : i2;
                m1 = c1 ? dd : m1;              i1 = c1 ? i : i1;
              }
            }
          }
        }
      }
      if (lane < 32) knnls[s_local * 32 + lane] = out_idx;
    }
    // ---- wait for transpose (pts_t ready); knnls/farls published by barrier
    if (t == 0){
      while (__hip_atomic_load(tdone, __ATOMIC_ACQUIRE, __HIP_MEMORY_SCOPE_AGENT) < 256)
        __builtin_amdgcn_s_sleep(16);
    }
    __syncthreads();
    __threadfence();
    // ---- gemm1 phase: 512 cols (= 16 s x K=32)
    const int col0 = sg * 512;
    {
      const int s_local = t >> 5, k = t & 31;
      const int idx = knnls[s_local * 32 + k];
      const int far = farls[s_local];
      const unsigned short* src = pts_t + ((size_t)(b * 4096 + idx)) * 64;
      #pragma unroll
      for (int j = 0; j < 8; j++) *(ushort8*)&Xl[t * XS + j * 8] = *(const ushort8*)&src[j * 8];
      ushort8 tail = {0,0,0,0,0,0,0,0};
      tail[0] = f2bf(__fsub_rn(xb[idx],        xb[far]));
      tail[1] = f2bf(__fsub_rn(xb[4096 + idx], xb[4096 + far]));
      tail[2] = f2bf(__fsub_rn(xb[8192 + idx], xb[8192 + far]));
      *(ushort8*)&Xl[t * XS + 64] = tail;
      ushort8 zz8 = {0,0,0,0,0,0,0,0};
      *(ushort8*)&Xl[t * XS + 72] = zz8;
      *(ushort8*)&Xl[t * XS + 80] = zz8;
      *(ushort8*)&Xl[t * XS + 88] = zz8;
    }
    const int lr = lane & 15, lg = lane >> 4;
    const int colw = w * 64;                   // 8 waves x 64 cols
    bfrag a[4][3];
    #pragma unroll
    for (int r = 0; r < 4; r++)
      #pragma unroll
      for (int kk = 0; kk < 3; kk++)
        a[r][kk] = *(const bfrag*)&Wb1[(16 * r + lr) * 96 + kk * 32 + lg * 8];
    __syncthreads();
    ffrag acc[4][4] = {};
    #pragma unroll
    for (int kk = 0; kk < 3; kk++){
      bfrag bb[4];
      #pragma unroll
      for (int cf = 0; cf < 4; cf++)
        bb[cf] = *(const bfrag*)&Xl[(colw + cf * 16 + lr) * XS + kk * 32 + lg * 8];
      #pragma unroll
      for (int r = 0; r < 4; r++)
        #pragma unroll
        for (int cf = 0; cf < 4; cf++)
          acc[r][cf] = __builtin_amdgcn_mfma_f32_16x16x32_bf16(a[r][kk], bb[cf], acc[r][cf], 0, 0, 0);
    }
    #pragma unroll
    for (int r = 0; r < 4; r++){
      const int o0 = 16 * r + 4 * lg;
      const ffrag bv = *(const ffrag*)&b1[o0];
      float sm[4] = {0,0,0,0}, sq[4] = {0,0,0,0};
      #pragma unroll
      for (int cf = 0; cf < 4; cf++){
        const int col = col0 + colw + cf * 16 + lr;
        unsigned pk[2];
        #pragma unroll
        for (int e = 0; e < 4; e++){
          float v = acc[r][cf][e] + bv[e];
          sm[e] += v; sq[e] += v * v;
          ((unsigned short*)pk)[e] = f2bf(v);
        }
        *(unsigned long long*)&z1[((size_t)(b * 32768) + col) * 64 + o0] = *(unsigned long long*)pk;
      }
      #pragma unroll
      for (int e = 0; e < 4; e++){
        float s1 = dppadd4(sm[e]);
        float q1 = dppadd4(sq[e]);
        if (lr == 0){ atomicAdd(&bsum[(o0 + e) * 2], s1); atomicAdd(&bsum[(o0 + e) * 2 + 1], q1); }
      }
    }
    __syncthreads();
    if (t < 128) atomicAdd(&stats1[sg * 128 + t], bsum[t]);
    return;
  }
  if (bid >= 16){
    // ---------------- transpose path (512 thr) ----------------
    unsigned short* tile = (unsigned short*)smem;       // 64*258*2 = 33024 B
    const int bid2 = bid - 16;
    const int b = bid2 >> 4, n0 = (bid2 & 15) * 256;
    {
      const int n = t & 255, ch = t >> 8;               // ch in {0,1}
      for (int it = 0; it < 32; it++){
        int c = it * 2 + ch;
        tile[c * 258 + n] = f2bf(pts[((size_t)(b * 64 + c)) * 4096 + n0 + n]);
      }
    }
    __syncthreads();
    const int nn = t >> 5, c2 = (t & 31) * 2;           // nn 0..15
    for (int rep = 0; rep < 16; rep++){
      int n = rep * 16 + nn;
      unsigned lo = tile[c2 * 258 + n], hi = tile[(c2 + 1) * 258 + n];
      ((unsigned*)pts_t)[(((size_t)(b * 4096 + n0 + n)) * 64 + c2) >> 1] = lo | (hi << 16);
    }
    __syncthreads();                                    // all stores issued
    if (t == 0){
      __threadfence();
      atomicAdd(tdone, 1);
    }
    return;
  }
  // ---------------- FPS path (512 thr, 8 pts/thr; R8-proven) ----------------
  float4* xl4 = (float4*)smem;                               // 65536 B
  unsigned long long* skey = (unsigned long long*)(smem + 65536);   // 32 B
  unsigned short* farhist = (unsigned short*)(smem + 65568);        // 2048 B
  const int b = bid;
  {
    const float* xb = xyz + (size_t)b * 3 * 4096;
    for (int j = 0; j < 8; j++){
      int i = j * 512 + t;
      float4 v; v.x = xb[i]; v.y = xb[4096 + i]; v.z = xb[8192 + i]; v.w = 0.f;
      xl4[i] = v;
    }
  }
  if (t == 0){
    skey[0] = 0xFFFFFFFF00000FFFull;   // lo=4095 -> far=0
    skey[1] = 0ull; skey[2] = 0ull; skey[3] = 0ull;
  }
  __syncthreads();
  float px[8], py[8], pz[8], dist[8];
  #pragma unroll
  for (int j = 0; j < 8; j++){
    int i = j * 512 + t;
    float4 v = xl4[i];
    px[j] = v.x; py[j] = v.y; pz[j] = v.z; dist[j] = 1e10f;
  }
  const unsigned a0 = 4095u - t;     // inv_j = a0 - j*512
  for (int s = 0; s < 1024; s++){
    const unsigned long long kg = skey[s & 3];
    const int far = 4095 - (int)(unsigned)(kg & 0xFFFFFFFFull);
    const float4 c4 = xl4[far];
    const float cx = c4.x, cy = c4.y, cz = c4.z;
    if (t == 0){
      farhist[s] = (unsigned short)far;
      skey[(s + 2) & 3] = 0ull;        // reset ring slot for step s+1's writers
      atomicExch(&farr[b * 1024 + s], far + 1);   // publish to combined consumers
    }
    float vm = -1.f;
    #pragma unroll
    for (int j = 0; j < 8; j++){
      float dx = __fsub_rn(px[j], cx), dy = __fsub_rn(py[j], cy), dz = __fsub_rn(pz[j], cz);
      float d = __fadd_rn(__fadd_rn(__fmul_rn(dx, dx), __fmul_rn(dy, dy)), __fmul_rn(dz, dz));
      float dm = fminf(dist[j], d); dist[j] = dm;
      vm = fmaxf(vm, dm);
    }
    const float wred = dppmax6(vm);
    const float wvm = __int_as_float(__builtin_amdgcn_readlane(__float_as_int(wred), 63));
    if (vm == wvm){                     // usually 1 lane/wave
      unsigned inv = 0u;
      #pragma unroll
      for (int j = 7; j >= 0; j--)
        if (dist[j] == wvm) inv = a0 - (unsigned)(j * 512);  // smallest j -> largest inv -> smallest idx
      atomicMax(&skey[(s + 1) & 3],
                (((unsigned long long)__float_as_uint(wvm)) << 32) | inv);
    }
    __syncthreads();
  }
  for (int s2 = t; s2 < 1024; s2 += 512){
    const int f = farhist[s2];
    const float4 c4 = xl4[f];
    out0[(b * 3 + 0) * 1024 + s2] = c4.x;
    out0[(b * 3 + 1) * 1024 + s2] = c4.y;
    out0[(b * 3 + 2) * 1024 + s2] = c4.z;
  }
}

// GEMM2: x = relu(a1*z1+c1), 64->64
__global__ __launch_bounds__(256) void gemm2_k(const unsigned short* __restrict__ z1,
    const unsigned short* __restrict__ Wb2, const float* __restrict__ b2, const float* __restrict__ p1,
    unsigned short* __restrict__ z2, float* __restrict__ stats){
  __shared__ unsigned short Xl[256 * XS];
  __shared__ float bsum[128];
  __shared__ float pa[64], pc[64];
  const int t = threadIdx.x, bid = blockIdx.x;
  const int b = bid >> 7, col0 = (bid & 127) * 256;
  if (t < 128) bsum[t] = 0.f;
  if (t < 64){ pa[t] = p1[t * 2]; pc[t] = p1[t * 2 + 1]; }
  const int lane = t & 63, lr = lane & 15, lg = lane >> 4;
  const int colw = (t >> 6) * 64;
  bfrag a[4][2];
  #pragma unroll
  for (int r = 0; r < 4; r++)
    #pragma unroll
    for (int kk = 0; kk < 2; kk++)
      a[r][kk] = *(const bfrag*)&Wb2[(16 * r + lr) * 64 + kk * 32 + lg * 8];
  __syncthreads();   // pa/pc ready
  {
    const size_t gcol = (size_t)b * 32768 + col0 + t;
    const unsigned short* src = z1 + gcol * 64;
    #pragma unroll
    for (int j = 0; j < 8; j++){
      ushort8 zv = *(const ushort8*)&src[j * 8];
      unsigned short ov[8];
      #pragma unroll
      for (int e = 0; e < 8; e++){
        int ch = j * 8 + e;
        float v = fmaxf(fmaf(pa[ch], bf2f(zv[e]), pc[ch]), 0.f);
        ov[e] = f2bf(v);
      }
      *(ushort8*)&Xl[t * XS + j * 8] = *(ushort8*)ov;
    }
  }
  __syncthreads();
  ffrag acc[4][4] = {};
  #pragma unroll
  for (int kk = 0; kk < 2; kk++){
    bfrag bb[4];
    #pragma unroll
    for (int cf = 0; cf < 4; cf++)
      bb[cf] = *(const bfrag*)&Xl[(colw + cf * 16 + lr) * XS + kk * 32 + lg * 8];
    #pragma unroll
    for (int r = 0; r < 4; r++)
      #pragma unroll
      for (int cf = 0; cf < 4; cf++)
        acc[r][cf] = __builtin_amdgcn_mfma_f32_16x16x32_bf16(a[r][kk], bb[cf], acc[r][cf], 0, 0, 0);
  }
  #pragma unroll
  for (int r = 0; r < 4; r++){
    const int o0 = 16 * r + 4 * lg;
    const ffrag bv = *(const ffrag*)&b2[o0];
    float sm[4] = {0,0,0,0}, sq[4] = {0,0,0,0};
    #pragma unroll
    for (int cf = 0; cf < 4; cf++){
      const int col = col0 + colw + cf * 16 + lr;
      unsigned pk[2];
      #pragma unroll
      for (int e = 0; e < 4; e++){
        float v = acc[r][cf][e] + bv[e];
        sm[e] += v; sq[e] += v * v;
        ((unsigned short*)pk)[e] = f2bf(v);
      }
      *(unsigned long long*)&z2[((size_t)(b * 32768) + col) * 64 + o0] = *(unsigned long long*)pk;
    }
    #pragma unroll
    for (int e = 0; e < 4; e++){
      float s1 = dppadd4(sm[e]);
      float q1 = dppadd4(sq[e]);
      if (lr == 0){ atomicAdd(&bsum[(o0 + e) * 2], s1); atomicAdd(&bsum[(o0 + e) * 2 + 1], q1); }
    }
  }
  __syncthreads();
  if (t < 128) atomicAdd(&stats[(bid & 63) * 128 + t], bsum[t]);
}

// GEMM3: 64->128, fused max/min over K (z3 never materialized)
__global__ __launch_bounds__(256) void gemm3_k(const unsigned short* __restrict__ z2,
    const unsigned short* __restrict__ Wb3, const float* __restrict__ b3, const float* __restrict__ p2,
    float* __restrict__ maxz, float* __restrict__ minz, float* __restrict__ stats){
  __shared__ unsigned short Xl[128 * XS];
  __shared__ float bsum[256];
  __shared__ float pa[64], pc[64];
  const int t = threadIdx.x, bid = blockIdx.x;
  const int b = bid >> 8, col0 = (bid & 255) * 128;
  bsum[t] = 0.f;
  if (t < 64){ pa[t] = p2[t * 2]; pc[t] = p2[t * 2 + 1]; }
  const int lane = t & 63, lr = lane & 15, lg = lane >> 4;
  const int w = t >> 6, wr = w >> 1, wc = w & 1;
  bfrag a[4][2];
  #pragma unroll
  for (int r = 0; r < 4; r++)
    #pragma unroll
    for (int kk = 0; kk < 2; kk++)
      a[r][kk] = *(const bfrag*)&Wb3[(wr * 64 + 16 * r + lr) * 64 + kk * 32 + lg * 8];
  __syncthreads();
  {
    const int colL = t & 127, half = t >> 7;
    const size_t gcol = (size_t)b * 32768 + col0 + colL;
    const unsigned short* src = z2 + gcol * 64 + half * 32;
    #pragma unroll
    for (int j = 0; j < 4; j++){
      ushort8 zv = *(const ushort8*)&src[j * 8];
      unsigned short ov[8];
      #pragma unroll
      for (int e = 0; e < 8; e++){
        int ch = half * 32 + j * 8 + e;
        float v = fmaxf(fmaf(pa[ch], bf2f(zv[e]), pc[ch]), 0.f);
        ov[e] = f2bf(v);
      }
      *(ushort8*)&Xl[colL * XS + half * 32 + j * 8] = *(ushort8*)ov;
    }
  }
  __syncthreads();
  ffrag acc[4][4] = {};
  #pragma unroll
  for (int kk = 0; kk < 2; kk++){
    bfrag bb[4];
    #pragma unroll
    for (int cf = 0; cf < 4; cf++)
      bb[cf] = *(const bfrag*)&Xl[(wc * 64 + cf * 16 + lr) * XS + kk * 32 + lg * 8];
    #pragma unroll
    for (int r = 0; r < 4; r++)
      #pragma unroll
      for (int cf = 0; cf < 4; cf++)
        acc[r][cf] = __builtin_amdgcn_mfma_f32_16x16x32_bf16(a[r][kk], bb[cf], acc[r][cf], 0, 0, 0);
  }
  const int s0 = (col0 + wc * 64) >> 5;    // 64 cols = 2 s values (K=32)
  #pragma unroll
  for (int r = 0; r < 4; r++){
    const int o0 = wr * 64 + 16 * r + 4 * lg;
    const ffrag bv = *(const ffrag*)&b3[(o0 & 127)];
    float vv[4][4];
    float sm[4] = {0,0,0,0}, sq[4] = {0,0,0,0};
    #pragma unroll
    for (int cf = 0; cf < 4; cf++)
      #pragma unroll
      for (int e = 0; e < 4; e++){
        float v = acc[r][cf][e] + bv[e];
        vv[cf][e] = v; sm[e] += v; sq[e] += v * v;
      }
    #pragma unroll
    for (int e = 0; e < 4; e++){
      float s1 = dppadd4(sm[e]);
      float q1 = dppadd4(sq[e]);
      if (lr == 0){ atomicAdd(&bsum[((o0 + e) & 127) * 2], s1); atomicAdd(&bsum[((o0 + e) & 127) * 2 + 1], q1); }
    }
    #pragma unroll
    for (int si = 0; si < 2; si++){
      ffrag mx, mn;
      #pragma unroll
      for (int e = 0; e < 4; e++){
        mx[e] = dppmax4(fmaxf(vv[si * 2][e], vv[si * 2 + 1][e]));
        mn[e] = dppmin4(fminf(vv[si * 2][e], vv[si * 2 + 1][e]));
      }
      if (lr == 0){
        *(ffrag*)&maxz[((size_t)(b * 1024) + s0 + si) * 128 + o0] = mx;
        *(ffrag*)&minz[((size_t)(b * 1024) + s0 + si) * 128 + o0] = mn;
      }
    }
  }
  __syncthreads();
  atomicAdd(&stats[(bid & 63) * 256 + t], bsum[t]);
}

// stats -> (a, c) affine params
template<int CH>
__global__ void stats_k(const float* __restrict__ stats, const float* __restrict__ gamma,
                        const float* __restrict__ beta, float* __restrict__ params){
  const int t = threadIdx.x;
  float sm = 0.f, sq = 0.f;
  for (int sl = 0; sl < 64; sl++){
    sm += stats[sl * (CH * 2) + t * 2];
    sq += stats[sl * (CH * 2) + t * 2 + 1];
  }
  const float cnt = 524288.f;
  float mean = sm / cnt;
  float var = sq / cnt - mean * mean;
  if (var < 0.f) var = 0.f;
  float inv = gamma[t] / sqrtf(var + 1e-5f);
  params[t * 2] = inv;
  params[t * 2 + 1] = beta[t] - mean * inv;
}

// final: out1[b][o][s] = relu(a3*sel+c3), LDS transpose for coalesced writes
__global__ __launch_bounds__(256) void final_k(const float* __restrict__ maxz,
    const float* __restrict__ minz, const float* __restrict__ p3, float* __restrict__ out1){
  __shared__ float tile[64][129];
  __shared__ float pa[128], pc[128];
  const int t = threadIdx.x, bid = blockIdx.x;
  const int b = bid >> 4, s0 = (bid & 15) * 64;
  if (t < 128){ pa[t] = p3[t * 2]; pc[t] = p3[t * 2 + 1]; }
  __syncthreads();
  const int o = t & 127, rr = t >> 7;
  for (int it = 0; it < 32; it++){
    int srow = it * 2 + rr;
    size_t base = ((size_t)(b * 1024) + s0 + srow) * 128 + o;
    float aa = pa[o], cc = pc[o];
    float m = (aa >= 0.f) ? maxz[base] : minz[base];
    tile[srow][o] = fmaxf(fmaf(aa, m, cc), 0.f);
  }
  __syncthreads();
  const int sc = t & 63, og = t >> 6;
  for (int it = 0; it < 32; it++){
    int o2 = it * 4 + og;
    out1[((size_t)(b * 128 + o2)) * 1024 + s0 + sc] = tile[sc][o2];
  }
}

extern "C" void kernel_launch(void* const* d_in, const int* in_sizes, int n_in,
                              void* d_out, int out_size, void* d_ws, size_t ws_size,
                              hipStream_t stream){
  const float* xyz = (const float*)d_in[0];
  const float* pts = (const float*)d_in[1];
  const float* W1 = (const float*)d_in[2];  const float* b1 = (const float*)d_in[3];
  const float* g1 = (const float*)d_in[4];  const float* be1 = (const float*)d_in[5];
  const float* W2 = (const float*)d_in[6];  const float* b2 = (const float*)d_in[7];
  const float* g2 = (const float*)d_in[8];  const float* be2 = (const float*)d_in[9];
  const float* W3 = (const float*)d_in[10]; const float* b3 = (const float*)d_in[11];
  const float* g3 = (const float*)d_in[12]; const float* be3 = (const float*)d_in[13];
  float* out0 = (float*)d_out;
  float* out1 = out0 + 16 * 3 * 1024;

  char* w = (char*)d_ws;
  size_t off = 0;
  auto alloc = [&](size_t bytes){ void* p = w + off; off = (off + bytes + 255) & ~(size_t)255; return p; };
  unsigned short* pts_t = (unsigned short*)alloc(8388608);      // [B][N][64] bf16
  unsigned short* z1    = (unsigned short*)alloc(67108864);      // [B*S*K][64] bf16
  unsigned short* z2    = (unsigned short*)alloc(67108864);
  float* maxz           = (float*)alloc(8388608);                // [B][S][128]
  float* minz           = (float*)alloc(8388608);
  unsigned short* Wb1   = (unsigned short*)alloc(12288);         // [64][96] bf16
  unsigned short* Wb2   = (unsigned short*)alloc(8192);          // [64][64]
  unsigned short* Wb3   = (unsigned short*)alloc(16384);         // [128][64]
  float* stats          = (float*)alloc(131072);                 // s1[64][128], s2 same, s3[64][256]
  float* params         = (float*)alloc(2048);
  int*   farr           = (int*)alloc(65536);                    // [B][S] fps progress (far+1)
  int*   tdone          = (int*)alloc(256);                      // transpose done counter
  if (ws_size < off) return;

  float* stats1 = stats;            // 8192 floats
  float* stats2 = stats + 8192;     // 8192 floats
  float* stats3 = stats + 16384;    // 16384 floats
  float* p1 = params, *p2 = params + 128, *p3 = params + 256;

  wconv_k<<<1, 256, 0, stream>>>(W1, W2, W3, Wb1, Wb2, Wb3, stats, farr, tdone);
  fused_k<<<1296, 512, 0, stream>>>(xyz, pts, pts_t, out0, farr, tdone, Wb1, b1, z1, stats1);
  stats_k<64><<<1, 64, 0, stream>>>(stats1, g1, be1, p1);
  gemm2_k<<<2048, 256, 0, stream>>>(z1, Wb2, b2, p1, z2, stats2);
  stats_k<64><<<1, 64, 0, stream>>>(stats2, g2, be2, p2);
  gemm3_k<<<4096, 256, 0, stream>>>(z2, Wb3, b3, p2, maxz, minz, stats3);
  stats_k<128><<<1, 128, 0, stream>>>(stats3, g3, be3, p3);
  final_k<<<256, 256, 0, stream>>>(maxz, minz, p3, out1);
}

// Round 17
// 737.794 us; speedup vs baseline: 2.8561x; 2.1301x over previous
//
#include <hip/hip_runtime.h>
#include <hip/hip_bf16.h>

// SetAbstraction: FPS -> kNN(32) -> gather -> 3x(conv1x1+BN+ReLU) -> maxpool(K)
// B=16 N=4096 S=1024 K=32 D_IN=64 MLP=[64,64,128]
// Mega-fused pipeline: fps publishes farr[s]; COMBINED blocks (one per 16 s)
// run kNN (no d-cache -> ~50 VGPR, no spill; results in LDS) then gemm1 for
// those s. Consumers wait only on always-resident fps + front transpose.
// Tail: stats1 | gemm2 | stats2 | gemm3 | stats3 | final.

typedef __attribute__((ext_vector_type(8))) short bfrag;    // 8 bf16 (MFMA A/B)
typedef __attribute__((ext_vector_type(4))) float ffrag;    // 4 f32 (MFMA C/D)
typedef __attribute__((ext_vector_type(8))) unsigned short ushort8;

#define XS 104   // LDS row stride in bf16 elems: 16B-aligned, 2-way bank conflict (free)

__device__ inline unsigned short f2bf(float f){
  union { float f; unsigned u; } v; v.f = f;
  unsigned r = v.u + 0x7fffu + ((v.u >> 16) & 1u);   // RNE
  return (unsigned short)(r >> 16);
}
__device__ inline float bf2f(unsigned short h){
  union { unsigned u; float f; } v; v.u = ((unsigned)h) << 16; return v.f;
}

// ---- DPP cross-lane (VALU-rate; no LDS pipe)
template<int CTRL> __device__ __forceinline__ int dppi(int v){
  return __builtin_amdgcn_update_dpp(0, v, CTRL, 0xF, 0xF, true);
}
template<int CTRL> __device__ __forceinline__ float dppf(float v){
  return __int_as_float(dppi<CTRL>(__float_as_int(v)));
}
__device__ __forceinline__ float dppmax6(float v){   // lane63 = wave max
  v = fmaxf(v, dppf<0xB1>(v)); v = fmaxf(v, dppf<0x4E>(v));
  v = fmaxf(v, dppf<0x141>(v)); v = fmaxf(v, dppf<0x140>(v));
  v = fmaxf(v, dppf<0x142>(v)); v = fmaxf(v, dppf<0x143>(v));
  return v;
}
__device__ __forceinline__ float dppmin6(float v){   // lane63 = wave min
  v = fminf(v, dppf<0xB1>(v)); v = fminf(v, dppf<0x4E>(v));
  v = fminf(v, dppf<0x141>(v)); v = fminf(v, dppf<0x140>(v));
  v = fminf(v, dppf<0x142>(v)); v = fminf(v, dppf<0x143>(v));
  return v;
}
__device__ __forceinline__ unsigned dppminu6(unsigned v){
  unsigned o;
  o = (unsigned)dppi<0xB1>((int)v);  v = v < o ? v : o;
  o = (unsigned)dppi<0x4E>((int)v);  v = v < o ? v : o;
  o = (unsigned)dppi<0x141>((int)v); v = v < o ? v : o;
  o = (unsigned)dppi<0x140>((int)v); v = v < o ? v : o;
  o = (unsigned)dppi<0x142>((int)v); v = v < o ? v : o;
  o = (unsigned)dppi<0x143>((int)v); v = v < o ? v : o;
  return v;                                          // lane63 = wave min
}
__device__ __forceinline__ float dppadd4(float v){   // all lanes: 16-lane-row sum
  v += dppf<0xB1>(v); v += dppf<0x4E>(v); v += dppf<0x141>(v); v += dppf<0x140>(v);
  return v;
}
__device__ __forceinline__ float dppmax4(float v){
  v = fmaxf(v, dppf<0xB1>(v)); v = fmaxf(v, dppf<0x4E>(v));
  v = fmaxf(v, dppf<0x141>(v)); v = fmaxf(v, dppf<0x140>(v));
  return v;
}
__device__ __forceinline__ float dppmin4(float v){
  v = fminf(v, dppf<0xB1>(v)); v = fminf(v, dppf<0x4E>(v));
  v = fminf(v, dppf<0x141>(v)); v = fminf(v, dppf<0x140>(v));
  return v;
}

// ---------------- wconv: W -> bf16 + zero stats/flags
__global__ __launch_bounds__(256) void wconv_k(const float* __restrict__ W1,
    const float* __restrict__ W2, const float* __restrict__ W3,
    unsigned short* __restrict__ Wb1, unsigned short* __restrict__ Wb2,
    unsigned short* __restrict__ Wb3, float* __restrict__ stats,
    int* __restrict__ farr, int* __restrict__ tdone){
  const int t = threadIdx.x;
  for (int i = t; i < 64 * 96; i += 256){
    int r = i / 96, c = i % 96;
    Wb1[i] = (c < 67) ? f2bf(W1[r * 67 + c]) : (unsigned short)0;
  }
  for (int i = t; i < 64 * 64; i += 256) Wb2[i] = f2bf(W2[i]);
  for (int i = t; i < 128 * 64; i += 256) Wb3[i] = f2bf(W3[i]);
  for (int i = t; i < 32768; i += 256) stats[i] = 0.f;
  for (int i = t; i < 16384; i += 256) farr[i] = 0;
  if (t == 0) tdone[0] = 0;
}

// ---------------- mega-fused kernel, 1296 blocks x 512 thr, 1 block/CU (~107KB LDS):
//  blocks   0..15   FPS (1/batch, serial 1024-step loop; publishes farr[s])
//  blocks  16..271  transpose pts -> pts_t bf16 (publishes tdone counter)
//  blocks 272..1295 COMBINED: kNN for 16 s (2/wave, NO d-cache -> low VGPR,
//                   results in LDS) then gemm1 for those 512 cols (z1+stats1).
__global__ __launch_bounds__(512) void fused_k(const float* __restrict__ xyz,
    const float* __restrict__ pts, unsigned short* __restrict__ pts_t,
    float* __restrict__ out0,
    int* __restrict__ farr, int* __restrict__ tdone,
    const unsigned short* __restrict__ Wb1, const float* __restrict__ b1,
    unsigned short* __restrict__ z1, float* __restrict__ stats1){
  __shared__ __align__(16) char smem[109184];   // >80KB: forces 1 block/CU
  const int t = threadIdx.x, bid = blockIdx.x;
  if (bid >= 272){
    // ---------------- COMBINED kNN + gemm1 path ----------------
    const int bid2 = bid - 272;                 // 0..1023
    const int sg = bid2 >> 4, b = bid2 & 15;    // s = sg*16 .. sg*16+15
    unsigned short* Xl = (unsigned short*)smem;            // 512*XS*2 = 106496 B
    float* bsum = (float*)(smem + 106496);                 // 128 f32 (512 B)
    int* knnls  = (int*)(smem + 107008);                   // 16*32 ints (2048 B)
    int* farls  = (int*)(smem + 109056);                   // 16 ints (64 B)
    const int w = t >> 6, lane = t & 63;
    const float* xb = xyz + (size_t)b * 3 * 4096;
    if (t < 128) bsum[t] = 0.f;
    // ---- kNN phase: each wave handles 2 s-values sequentially (no d-cache)
    for (int rep = 0; rep < 2; rep++){
      const int s_local = w + rep * 8;
      const int s = sg * 16 + s_local;
      int fidx;
      while ((fidx = atomicAdd(&farr[b * 1024 + s], 0)) == 0)
        __builtin_amdgcn_s_sleep(16);
      const int far = fidx - 1;
      if (lane == 0) farls[s_local] = far;
      const float cx = xb[far], cy = xb[4096 + far], cz = xb[8192 + far];
      const float sqc = __fadd_rn(__fadd_rn(__fmul_rn(cx, cx), __fmul_rn(cy, cy)), __fmul_rn(cz, cz));
      float m1 = 3e38f, m2 = 3e38f, m3 = 3e38f, m4 = 3e38f;
      int i1 = 0x7fffffff, i2 = 0x7fffffff, i3 = 0x7fffffff, i4 = 0x7fffffff;
      #pragma unroll 4
      for (int j = 0; j < 64; j++){
        int i = j * 64 + lane;
        float x = xb[i], y = xb[4096 + i], z = xb[8192 + i];
        float sqn = __fadd_rn(__fadd_rn(__fmul_rn(x, x), __fmul_rn(y, y)), __fmul_rn(z, z));
        float dot = __fadd_rn(__fadd_rn(__fmul_rn(cx, x), __fmul_rn(cy, y)), __fmul_rn(cz, z));
        float dd = __fsub_rn(__fadd_rn(sqc, sqn), __fmul_rn(2.0f, dot));
        bool c1 = dd < m1, c2 = dd < m2, c3 = dd < m3, c4 = dd < m4;
        m4 = c4 ? (c3 ? m3 : dd) : m4;  i4 = c4 ? (c3 ? i3 : i) : i4;
        m3 = c3 ? (c2 ? m2 : dd) : m3;  i3 = c3 ? (c2 ? i2 : i) : i3;
        m2 = c2 ? (c1 ? m1 : dd) : m2;  i2 = c2 ? (c1 ? i1 : i) : i2;
        m1 = c1 ? dd : m1;              i1 = c1 ? i : i1;
      }
      unsigned long long taken = 0ull;
      int out_idx = 0;
      #pragma unroll 1
      for (int r = 0; r < 32; r++){
        const float gred = dppmin6(m1);
        const float gmin = __int_as_float(__builtin_amdgcn_readlane(__float_as_int(gred), 63));
        const bool cand = (m1 == gmin);
        const unsigned long long cm = __ballot(cand);
        int widx;
        if (__popcll(cm) == 1){
          widx = __builtin_amdgcn_readlane(i1, (int)(__ffsll(cm) - 1));
        } else {                            // exact-tie rare path: min index among candidates
          unsigned ci = cand ? (unsigned)i1 : 0xFFFFFFFFu;
          widx = (int)__builtin_amdgcn_readlane((int)dppminu6(ci), 63);
        }
        if (lane == r) out_idx = widx;
        if (i1 == widx){                    // unique owner pops
          taken |= 1ull << (widx >> 6);
          m1 = m2; i1 = i2; m2 = m3; i2 = i3; m3 = m4; i3 = i4;
          m4 = 3e38f; i4 = 0x7fffffff;
          if (i1 == 0x7fffffff){            // spares exhausted (rare): recompute + refill
            m1 = 3e38f; m2 = 3e38f; m3 = 3e38f; m4 = 3e38f;
            i1 = 0x7fffffff; i2 = 0x7fffffff; i3 = 0x7fffffff; i4 = 0x7fffffff;
            #pragma unroll 1
            for (int j = 0; j < 64; j++){
              if (!((taken >> j) & 1ull)){
                int i = j * 64 + lane;
                float x = xb[i], y = xb[4096 + i], z = xb[8192 + i];
                float sqn = __fadd_rn(__fadd_rn(__fmul_rn(x, x), __fmul_rn(y, y)), __fmul_rn(z, z));
                float dot = __fadd_rn(__fadd_rn(__fmul_rn(cx, x), __fmul_rn(cy, y)), __fmul_rn(cz, z));
                float dd = __fsub_rn(__fadd_rn(sqc, sqn), __fmul_rn(2.0f, dot));
                bool c1 = dd < m1, c2 = dd < m2, c3 = dd < m3, c4 = dd < m4;
                m4 = c4 ? (c3 ? m3 : dd) : m4;  i4 = c4 ? (c3 ? i3 : i) : i4;
                m3 = c3 ? (c2 ? m2 : dd) : m3;  i3 = c3 ? (c2 ? i2 : i) : i3;
                m2 = c2 ? (c1 ? m1 : dd) : m2;  i2 = c2 ? (c1 ? i1 : i) : i2;
                m1 = c1 ? dd : m1;              i1 = c1 ? i : i1;
              }
            }
          }
        }
      }
      if (lane < 32) knnls[s_local * 32 + lane] = out_idx;
    }
    // ---- wait for transpose (pts_t ready); knnls/farls published by barrier
    if (t == 0){
      while (__hip_atomic_load(tdone, __ATOMIC_ACQUIRE, __HIP_MEMORY_SCOPE_AGENT) < 256)
        __builtin_amdgcn_s_sleep(16);
    }
    __syncthreads();
    __threadfence();
    // ---- gemm1 phase: 512 cols (= 16 s x K=32)
    const int col0 = sg * 512;
    {
      const int s_local = t >> 5, k = t & 31;
      const int idx = knnls[s_local * 32 + k];
      const int far = farls[s_local];
      const unsigned short* src = pts_t + ((size_t)(b * 4096 + idx)) * 64;
      #pragma unroll
      for (int j = 0; j < 8; j++) *(ushort8*)&Xl[t * XS + j * 8] = *(const ushort8*)&src[j * 8];
      ushort8 tail = {0,0,0,0,0,0,0,0};
      tail[0] = f2bf(__fsub_rn(xb[idx],        xb[far]));
      tail[1] = f2bf(__fsub_rn(xb[4096 + idx], xb[4096 + far]));
      tail[2] = f2bf(__fsub_rn(xb[8192 + idx], xb[8192 + far]));
      *(ushort8*)&Xl[t * XS + 64] = tail;
      ushort8 zz8 = {0,0,0,0,0,0,0,0};
      *(ushort8*)&Xl[t * XS + 72] = zz8;
      *(ushort8*)&Xl[t * XS + 80] = zz8;
      *(ushort8*)&Xl[t * XS + 88] = zz8;
    }
    const int lr = lane & 15, lg = lane >> 4;
    const int colw = w * 64;                   // 8 waves x 64 cols
    bfrag a[4][3];
    #pragma unroll
    for (int r = 0; r < 4; r++)
      #pragma unroll
      for (int kk = 0; kk < 3; kk++)
        a[r][kk] = *(const bfrag*)&Wb1[(16 * r + lr) * 96 + kk * 32 + lg * 8];
    __syncthreads();
    ffrag acc[4][4] = {};
    #pragma unroll
    for (int kk = 0; kk < 3; kk++){
      bfrag bb[4];
      #pragma unroll
      for (int cf = 0; cf < 4; cf++)
        bb[cf] = *(const bfrag*)&Xl[(colw + cf * 16 + lr) * XS + kk * 32 + lg * 8];
      #pragma unroll
      for (int r = 0; r < 4; r++)
        #pragma unroll
        for (int cf = 0; cf < 4; cf++)
          acc[r][cf] = __builtin_amdgcn_mfma_f32_16x16x32_bf16(a[r][kk], bb[cf], acc[r][cf], 0, 0, 0);
    }
    #pragma unroll
    for (int r = 0; r < 4; r++){
      const int o0 = 16 * r + 4 * lg;
      const ffrag bv = *(const ffrag*)&b1[o0];
      float sm[4] = {0,0,0,0}, sq[4] = {0,0,0,0};
      #pragma unroll
      for (int cf = 0; cf < 4; cf++){
        const int col = col0 + colw + cf * 16 + lr;
        unsigned pk[2];
        #pragma unroll
        for (int e = 0; e < 4; e++){
          float v = acc[r][cf][e] + bv[e];
          sm[e] += v; sq[e] += v * v;
          ((unsigned short*)pk)[e] = f2bf(v);
        }
        *(unsigned long long*)&z1[((size_t)(b * 32768) + col) * 64 + o0] = *(unsigned long long*)pk;
      }
      #pragma unroll
      for (int e = 0; e < 4; e++){
        float s1 = dppadd4(sm[e]);
        float q1 = dppadd4(sq[e]);
        if (lr == 0){ atomicAdd(&bsum[(o0 + e) * 2], s1); atomicAdd(&bsum[(o0 + e) * 2 + 1], q1); }
      }
    }
    __syncthreads();
    if (t < 128) atomicAdd(&stats1[sg * 128 + t], bsum[t]);
    return;
  }
  if (bid >= 16){
    // ---------------- transpose path (512 thr) ----------------
    unsigned short* tile = (unsigned short*)smem;       // 64*258*2 = 33024 B
    const int bid2 = bid - 16;
    const int b = bid2 >> 4, n0 = (bid2 & 15) * 256;
    {
      const int n = t & 255, ch = t >> 8;               // ch in {0,1}
      for (int it = 0; it < 32; it++){
        int c = it * 2 + ch;
        tile[c * 258 + n] = f2bf(pts[((size_t)(b * 64 + c)) * 4096 + n0 + n]);
      }
    }
    __syncthreads();
    const int nn = t >> 5, c2 = (t & 31) * 2;           // nn 0..15
    for (int rep = 0; rep < 16; rep++){
      int n = rep * 16 + nn;
      unsigned lo = tile[c2 * 258 + n], hi = tile[(c2 + 1) * 258 + n];
      ((unsigned*)pts_t)[(((size_t)(b * 4096 + n0 + n)) * 64 + c2) >> 1] = lo | (hi << 16);
    }
    __syncthreads();                                    // all stores issued
    if (t == 0){
      __threadfence();
      atomicAdd(tdone, 1);
    }
    return;
  }
  // ---------------- FPS path (512 thr, 8 pts/thr; R8-proven) ----------------
  float4* xl4 = (float4*)smem;                               // 65536 B
  unsigned long long* skey = (unsigned long long*)(smem + 65536);   // 32 B
  unsigned short* farhist = (unsigned short*)(smem + 65568);        // 2048 B
  const int b = bid;
  {
    const float* xb = xyz + (size_t)b * 3 * 4096;
    for (int j = 0; j < 8; j++){
      int i = j * 512 + t;
      float4 v; v.x = xb[i]; v.y = xb[4096 + i]; v.z = xb[8192 + i]; v.w = 0.f;
      xl4[i] = v;
    }
  }
  if (t == 0){
    skey[0] = 0xFFFFFFFF00000FFFull;   // lo=4095 -> far=0
    skey[1] = 0ull; skey[2] = 0ull; skey[3] = 0ull;
  }
  __syncthreads();
  float px[8], py[8], pz[8], dist[8];
  #pragma unroll
  for (int j = 0; j < 8; j++){
    int i = j * 512 + t;
    float4 v = xl4[i];
    px[j] = v.x; py[j] = v.y; pz[j] = v.z; dist[j] = 1e10f;
  }
  const unsigned a0 = 4095u - t;     // inv_j = a0 - j*512
  for (int s = 0; s < 1024; s++){
    const unsigned long long kg = skey[s & 3];
    const int far = 4095 - (int)(unsigned)(kg & 0xFFFFFFFFull);
    const float4 c4 = xl4[far];
    const float cx = c4.x, cy = c4.y, cz = c4.z;
    if (t == 0){
      farhist[s] = (unsigned short)far;
      skey[(s + 2) & 3] = 0ull;        // reset ring slot for step s+1's writers
      atomicExch(&farr[b * 1024 + s], far + 1);   // publish to combined consumers
    }
    float vm = -1.f;
    #pragma unroll
    for (int j = 0; j < 8; j++){
      float dx = __fsub_rn(px[j], cx), dy = __fsub_rn(py[j], cy), dz = __fsub_rn(pz[j], cz);
      float d = __fadd_rn(__fadd_rn(__fmul_rn(dx, dx), __fmul_rn(dy, dy)), __fmul_rn(dz, dz));
      float dm = fminf(dist[j], d); dist[j] = dm;
      vm = fmaxf(vm, dm);
    }
    const float wred = dppmax6(vm);
    const float wvm = __int_as_float(__builtin_amdgcn_readlane(__float_as_int(wred), 63));
    if (vm == wvm){                     // usually 1 lane/wave
      unsigned inv = 0u;
      #pragma unroll
      for (int j = 7; j >= 0; j--)
        if (dist[j] == wvm) inv = a0 - (unsigned)(j * 512);  // smallest j -> largest inv -> smallest idx
      atomicMax(&skey[(s + 1) & 3],
                (((unsigned long long)__float_as_uint(wvm)) << 32) | inv);
    }
    __syncthreads();
  }
  for (int s2 = t; s2 < 1024; s2 += 512){
    const int f = farhist[s2];
    const float4 c4 = xl4[f];
    out0[(b * 3 + 0) * 1024 + s2] = c4.x;
    out0[(b * 3 + 1) * 1024 + s2] = c4.y;
    out0[(b * 3 + 2) * 1024 + s2] = c4.z;
  }
}

// GEMM2: x = relu(a1*z1+c1), 64->64
__global__ __launch_bounds__(256) void gemm2_k(const unsigned short* __restrict__ z1,
    const unsigned short* __restrict__ Wb2, const float* __restrict__ b2, const float* __restrict__ p1,
    unsigned short* __restrict__ z2, float* __restrict__ stats){
  __shared__ unsigned short Xl[256 * XS];
  __shared__ float bsum[128];
  __shared__ float pa[64], pc[64];
  const int t = threadIdx.x, bid = blockIdx.x;
  const int b = bid >> 7, col0 = (bid & 127) * 256;
  if (t < 128) bsum[t] = 0.f;
  if (t < 64){ pa[t] = p1[t * 2]; pc[t] = p1[t * 2 + 1]; }
  const int lane = t & 63, lr = lane & 15, lg = lane >> 4;
  const int colw = (t >> 6) * 64;
  bfrag a[4][2];
  #pragma unroll
  for (int r = 0; r < 4; r++)
    #pragma unroll
    for (int kk = 0; kk < 2; kk++)
      a[r][kk] = *(const bfrag*)&Wb2[(16 * r + lr) * 64 + kk * 32 + lg * 8];
  __syncthreads();   // pa/pc ready
  {
    const size_t gcol = (size_t)b * 32768 + col0 + t;
    const unsigned short* src = z1 + gcol * 64;
    #pragma unroll
    for (int j = 0; j < 8; j++){
      ushort8 zv = *(const ushort8*)&src[j * 8];
      unsigned short ov[8];
      #pragma unroll
      for (int e = 0; e < 8; e++){
        int ch = j * 8 + e;
        float v = fmaxf(fmaf(pa[ch], bf2f(zv[e]), pc[ch]), 0.f);
        ov[e] = f2bf(v);
      }
      *(ushort8*)&Xl[t * XS + j * 8] = *(ushort8*)ov;
    }
  }
  __syncthreads();
  ffrag acc[4][4] = {};
  #pragma unroll
  for (int kk = 0; kk < 2; kk++){
    bfrag bb[4];
    #pragma unroll
    for (int cf = 0; cf < 4; cf++)
      bb[cf] = *(const bfrag*)&Xl[(colw + cf * 16 + lr) * XS + kk * 32 + lg * 8];
    #pragma unroll
    for (int r = 0; r < 4; r++)
      #pragma unroll
      for (int cf = 0; cf < 4; cf++)
        acc[r][cf] = __builtin_amdgcn_mfma_f32_16x16x32_bf16(a[r][kk], bb[cf], acc[r][cf], 0, 0, 0);
  }
  #pragma unroll
  for (int r = 0; r < 4; r++){
    const int o0 = 16 * r + 4 * lg;
    const ffrag bv = *(const ffrag*)&b2[o0];
    float sm[4] = {0,0,0,0}, sq[4] = {0,0,0,0};
    #pragma unroll
    for (int cf = 0; cf < 4; cf++){
      const int col = col0 + colw + cf * 16 + lr;
      unsigned pk[2];
      #pragma unroll
      for (int e = 0; e < 4; e++){
        float v = acc[r][cf][e] + bv[e];
        sm[e] += v; sq[e] += v * v;
        ((unsigned short*)pk)[e] = f2bf(v);
      }
      *(unsigned long long*)&z2[((size_t)(b * 32768) + col) * 64 + o0] = *(unsigned long long*)pk;
    }
    #pragma unroll
    for (int e = 0; e < 4; e++){
      float s1 = dppadd4(sm[e]);
      float q1 = dppadd4(sq[e]);
      if (lr == 0){ atomicAdd(&bsum[(o0 + e) * 2], s1); atomicAdd(&bsum[(o0 + e) * 2 + 1], q1); }
    }
  }
  __syncthreads();
  if (t < 128) atomicAdd(&stats[(bid & 63) * 128 + t], bsum[t]);
}

// GEMM3: 64->128, fused max/min over K (z3 never materialized)
__global__ __launch_bounds__(256) void gemm3_k(const unsigned short* __restrict__ z2,
    const unsigned short* __restrict__ Wb3, const float* __restrict__ b3, const float* __restrict__ p2,
    float* __restrict__ maxz, float* __restrict__ minz, float* __restrict__ stats){
  __shared__ unsigned short Xl[128 * XS];
  __shared__ float bsum[256];
  __shared__ float pa[64], pc[64];
  const int t = threadIdx.x, bid = blockIdx.x;
  const int b = bid >> 8, col0 = (bid & 255) * 128;
  bsum[t] = 0.f;
  if (t < 64){ pa[t] = p2[t * 2]; pc[t] = p2[t * 2 + 1]; }
  const int lane = t & 63, lr = lane & 15, lg = lane >> 4;
  const int w = t >> 6, wr = w >> 1, wc = w & 1;
  bfrag a[4][2];
  #pragma unroll
  for (int r = 0; r < 4; r++)
    #pragma unroll
    for (int kk = 0; kk < 2; kk++)
      a[r][kk] = *(const bfrag*)&Wb3[(wr * 64 + 16 * r + lr) * 64 + kk * 32 + lg * 8];
  __syncthreads();
  {
    const int colL = t & 127, half = t >> 7;
    const size_t gcol = (size_t)b * 32768 + col0 + colL;
    const unsigned short* src = z2 + gcol * 64 + half * 32;
    #pragma unroll
    for (int j = 0; j < 4; j++){
      ushort8 zv = *(const ushort8*)&src[j * 8];
      unsigned short ov[8];
      #pragma unroll
      for (int e = 0; e < 8; e++){
        int ch = half * 32 + j * 8 + e;
        float v = fmaxf(fmaf(pa[ch], bf2f(zv[e]), pc[ch]), 0.f);
        ov[e] = f2bf(v);
      }
      *(ushort8*)&Xl[colL * XS + half * 32 + j * 8] = *(ushort8*)ov;
    }
  }
  __syncthreads();
  ffrag acc[4][4] = {};
  #pragma unroll
  for (int kk = 0; kk < 2; kk++){
    bfrag bb[4];
    #pragma unroll
    for (int cf = 0; cf < 4; cf++)
      bb[cf] = *(const bfrag*)&Xl[(wc * 64 + cf * 16 + lr) * XS + kk * 32 + lg * 8];
    #pragma unroll
    for (int r = 0; r < 4; r++)
      #pragma unroll
      for (int cf = 0; cf < 4; cf++)
        acc[r][cf] = __builtin_amdgcn_mfma_f32_16x16x32_bf16(a[r][kk], bb[cf], acc[r][cf], 0, 0, 0);
  }
  const int s0 = (col0 + wc * 64) >> 5;    // 64 cols = 2 s values (K=32)
  #pragma unroll
  for (int r = 0; r < 4; r++){
    const int o0 = wr * 64 + 16 * r + 4 * lg;
    const ffrag bv = *(const ffrag*)&b3[(o0 & 127)];
    float vv[4][4];
    float sm[4] = {0,0,0,0}, sq[4] = {0,0,0,0};
    #pragma unroll
    for (int cf = 0; cf < 4; cf++)
      #pragma unroll
      for (int e = 0; e < 4; e++){
        float v = acc[r][cf][e] + bv[e];
        vv[cf][e] = v; sm[e] += v; sq[e] += v * v;
      }
    #pragma unroll
    for (int e = 0; e < 4; e++){
      float s1 = dppadd4(sm[e]);
      float q1 = dppadd4(sq[e]);
      if (lr == 0){ atomicAdd(&bsum[((o0 + e) & 127) * 2], s1); atomicAdd(&bsum[((o0 + e) & 127) * 2 + 1], q1); }
    }
    #pragma unroll
    for (int si = 0; si < 2; si++){
      ffrag mx, mn;
      #pragma unroll
      for (int e = 0; e < 4; e++){
        mx[e] = dppmax4(fmaxf(vv[si * 2][e], vv[si * 2 + 1][e]));
        mn[e] = dppmin4(fminf(vv[si * 2][e], vv[si * 2 + 1][e]));
      }
      if (lr == 0){
        *(ffrag*)&maxz[((size_t)(b * 1024) + s0 + si) * 128 + o0] = mx;
        *(ffrag*)&minz[((size_t)(b * 1024) + s0 + si) * 128 + o0] = mn;
      }
    }
  }
  __syncthreads();
  atomicAdd(&stats[(bid & 63) * 256 + t], bsum[t]);
}

// stats -> (a, c) affine params
template<int CH>
__global__ void stats_k(const float* __restrict__ stats, const float* __restrict__ gamma,
                        const float* __restrict__ beta, float* __restrict__ params){
  const int t = threadIdx.x;
  float sm = 0.f, sq = 0.f;
  for (int sl = 0; sl < 64; sl++){
    sm += stats[sl * (CH * 2) + t * 2];
    sq += stats[sl * (CH * 2) + t * 2 + 1];
  }
  const float cnt = 524288.f;
  float mean = sm / cnt;
  float var = sq / cnt - mean * mean;
  if (var < 0.f) var = 0.f;
  float inv = gamma[t] / sqrtf(var + 1e-5f);
  params[t * 2] = inv;
  params[t * 2 + 1] = beta[t] - mean * inv;
}

// final: out1[b][o][s] = relu(a3*sel+c3), LDS transpose for coalesced writes
__global__ __launch_bounds__(256) void final_k(const float* __restrict__ maxz,
    const float* __restrict__ minz, const float* __restrict__ p3, float* __restrict__ out1){
  __shared__ float tile[64][129];
  __shared__ float pa[128], pc[128];
  const int t = threadIdx.x, bid = blockIdx.x;
  const int b = bid >> 4, s0 = (bid & 15) * 64;
  if (t < 128){ pa[t] = p3[t * 2]; pc[t] = p3[t * 2 + 1]; }
  __syncthreads();
  const int o = t & 127, rr = t >> 7;
  for (int it = 0; it < 32; it++){
    int srow = it * 2 + rr;
    size_t base = ((size_t)(b * 1024) + s0 + srow) * 128 + o;
    float aa = pa[o], cc = pc[o];
    float m = (aa >= 0.f) ? maxz[base] : minz[base];
    tile[srow][o] = fmaxf(fmaf(aa, m, cc), 0.f);
  }
  __syncthreads();
  const int sc = t & 63, og = t >> 6;
  for (int it = 0; it < 32; it++){
    int o2 = it * 4 + og;
    out1[((size_t)(b * 128 + o2)) * 1024 + s0 + sc] = tile[sc][o2];
  }
}

extern "C" void kernel_launch(void* const* d_in, const int* in_sizes, int n_in,
                              void* d_out, int out_size, void* d_ws, size_t ws_size,
                              hipStream_t stream){
  const float* xyz = (const float*)d_in[0];
  const float* pts = (const float*)d_in[1];
  const float* W1 = (const float*)d_in[2];  const float* b1 = (const float*)d_in[3];
  const float* g1 = (const float*)d_in[4];  const float* be1 = (const float*)d_in[5];
  const float* W2 = (const float*)d_in[6];  const float* b2 = (const float*)d_in[7];
  const float* g2 = (const float*)d_in[8];  const float* be2 = (const float*)d_in[9];
  const float* W3 = (const float*)d_in[10]; const float* b3 = (const float*)d_in[11];
  const float* g3 = (const float*)d_in[12]; const float* be3 = (const float*)d_in[13];
  float* out0 = (float*)d_out;
  float* out1 = out0 + 16 * 3 * 1024;

  char* w = (char*)d_ws;
  size_t off = 0;
  auto alloc = [&](size_t bytes){ void* p = w + off; off = (off + bytes + 255) & ~(size_t)255; return p; };
  unsigned short* pts_t = (unsigned short*)alloc(8388608);      // [B][N][64] bf16
  unsigned short* z1    = (unsigned short*)alloc(67108864);      // [B*S*K][64] bf16
  unsigned short* z2    = (unsigned short*)alloc(67108864);
  float* maxz           = (float*)alloc(8388608);                // [B][S][128]
  float* minz           = (float*)alloc(8388608);
  unsigned short* Wb1   = (unsigned short*)alloc(12288);         // [64][96] bf16
  unsigned short* Wb2   = (unsigned short*)alloc(8192);          // [64][64]
  unsigned short* Wb3   = (unsigned short*)alloc(16384);         // [128][64]
  float* stats          = (float*)alloc(131072);                 // s1[64][128], s2 same, s3[64][256]
  float* params         = (float*)alloc(2048);
  int*   farr           = (int*)alloc(65536);                    // [B][S] fps progress (far+1)
  int*   tdone          = (int*)alloc(256);                      // transpose done counter
  if (ws_size < off) return;

  float* stats1 = stats;            // 8192 floats
  float* stats2 = stats + 8192;     // 8192 floats
  float* stats3 = stats + 16384;    // 16384 floats
  float* p1 = params, *p2 = params + 128, *p3 = params + 256;

  wconv_k<<<1, 256, 0, stream>>>(W1, W2, W3, Wb1, Wb2, Wb3, stats, farr, tdone);
  fused_k<<<1296, 512, 0, stream>>>(xyz, pts, pts_t, out0, farr, tdone, Wb1, b1, z1, stats1);
  stats_k<64><<<1, 64, 0, stream>>>(stats1, g1, be1, p1);
  gemm2_k<<<2048, 256, 0, stream>>>(z1, Wb2, b2, p1, z2, stats2);
  stats_k<64><<<1, 64, 0, stream>>>(stats2, g2, be2, p2);
  gemm3_k<<<4096, 256, 0, stream>>>(z2, Wb3, b3, p2, maxz, minz, stats3);
  stats_k<128><<<1, 128, 0, stream>>>(stats3, g3, be3, p3);
  final_k<<<256, 256, 0, stream>>>(maxz, minz, p3, out1);
}